// Round 6
// baseline (760.349 us; speedup 1.0000x reference)
//
#include <hip/hip_runtime.h>
#include <math.h>

#define B_   32
#define L_   2048
#define DSEQ 1024
#define DGLB 1024
#define H_   16
#define DK_  64
#define DV_  64
#define LT   64
#define NT   (L_/LT)      // 32
#define PSTRIDE 66        // m, s, y[64]

using u16    = unsigned short;
using bf16x8 = __attribute__((ext_vector_type(8))) short;
using f32x4  = __attribute__((ext_vector_type(4))) float;

__device__ __forceinline__ u16 f2bf(float x) {
  union { float f; unsigned int u; } v; v.f = x;
  return (u16)((v.u + 0x7fffu + ((v.u >> 16) & 1u)) >> 16);   // RNE
}

// Wc[h][j][d] (bf16, k-contiguous): j<64 -> Wk[h,:,j], else Wv[h,:,j-64]
__global__ void pack_w_kernel(const float* __restrict__ Wk,
                              const float* __restrict__ Wv,
                              u16* __restrict__ Wc) {
  const int h = blockIdx.x, j = blockIdx.y;
  const float* src = (j < DK_) ? (Wk + (size_t)h*DSEQ*DK_ + j)
                               : (Wv + (size_t)h*DSEQ*DV_ + (j - DK_));
  u16* dst = Wc + ((size_t)h*128 + j)*DSEQ;
  for (int d = threadIdx.x; d < DSEQ; d += blockDim.x)
    dst[d] = f2bf(src[(size_t)d*64]);
}

// S (fp32) -> Sb (bf16), flat; 8-elem granules, coalesced
__global__ void s2bf_kernel(const float* __restrict__ S, u16* __restrict__ Sb) {
  const size_t G = (size_t)B_*L_*DSEQ/8;
  for (size_t i = (size_t)blockIdx.x*256 + threadIdx.x; i < G; i += (size_t)4096*256) {
    const float4* sp = (const float4*)(S + i*8);
    float4 v0 = sp[0], v1 = sp[1];
    bf16x8 wv;
    wv[0]=(short)f2bf(v0.x); wv[1]=(short)f2bf(v0.y);
    wv[2]=(short)f2bf(v0.z); wv[3]=(short)f2bf(v0.w);
    wv[4]=(short)f2bf(v1.x); wv[5]=(short)f2bf(v1.y);
    wv[6]=(short)f2bf(v1.z); wv[7]=(short)f2bf(v1.w);
    *(bf16x8*)(Sb + i*8) = wv;
  }
}

// Q[b][h][k] = tanh(sum_d X[b,d]*Wq[h,d,k]); grid (H, B/4), block 64
__global__ void q_proj_kernel(const float* __restrict__ X,
                              const float* __restrict__ Wq,
                              float* __restrict__ Q) {
  const int h = blockIdx.x, b0 = blockIdx.y*4, k = threadIdx.x;
  const float* w = Wq + (size_t)h*DGLB*DK_ + k;
  float a0=0.f, a1=0.f, a2=0.f, a3=0.f;
  for (int d = 0; d < DGLB; ++d) {
    float wv = w[(size_t)d*DK_];
    a0 += X[(size_t)(b0+0)*DGLB + d]*wv;
    a1 += X[(size_t)(b0+1)*DGLB + d]*wv;
    a2 += X[(size_t)(b0+2)*DGLB + d]*wv;
    a3 += X[(size_t)(b0+3)*DGLB + d]*wv;
  }
  Q[((size_t)(b0+0)*H_+h)*DK_+k] = tanhf(a0);
  Q[((size_t)(b0+1)*H_+h)*DK_+k] = tanhf(a1);
  Q[((size_t)(b0+2)*H_+h)*DK_+k] = tanhf(a2);
  Q[((size_t)(b0+3)*H_+h)*DK_+k] = tanhf(a3);
}

// grid: 8192 linear blocks, 256 threads = 4 waves.
// slot=id&7 -> XCD; each slot owns 2 heads (Wc slice 512 KB, L2-hot).
// Wave w = (head hp=w>>1, K|V=w&1); tile 64 rows x 64 cols, acc[4][4].
// __launch_bounds__(256,2): 2 waves/EU -> 256-reg budget (NO spill; r2
// measured this live set at 176 unified) and 2 blocks/CU (LDS 2x64KB)
// so one block stages while the other runs its k-loop.
// S staged bf16 via global_load_lds, swizzle pre-applied on the global
// source granule (T21: linear LDS dest + inverse-swizzled source).
template<int BF16SRC>
__global__ __launch_bounds__(256, 2) void fused_kernel(
    const float* __restrict__ S, const u16* __restrict__ Sb,
    const u16* __restrict__ Wc, const float* __restrict__ Q,
    float* __restrict__ part) {
  __shared__ u16   Slds[LT*512];     // 64 KB, rows 1 KB
  __shared__ float lpart[2][64];

  const int id   = blockIdx.x;
  const int slot = id & 7;           // XCD / head-pair group
  const int rest = id >> 3;
  const int t    = rest & (NT-1), b = rest >> 5;

  const int tid  = threadIdx.x;
  const int wave = tid >> 6, lane = tid & 63;
  const int lhi  = lane >> 4, llo = lane & 15;
  const int isV  = wave & 1,  hp  = wave >> 1;
  const int h    = slot*2 + hp;

  const u16* wp = Wc + ((size_t)(h*128 + isV*64 + llo))*DSEQ + lhi*8;
  const int swz = llo << 4;
  int arow[4];
  #pragma unroll
  for (int rt = 0; rt < 4; ++rt) arow[rt] = (rt*16 + llo)*1024;  // bytes

  f32x4 acc[4][4];
  #pragma unroll
  for (int rt = 0; rt < 4; ++rt)
    #pragma unroll
    for (int c = 0; c < 4; ++c) acc[rt][c] = {0.f,0.f,0.f,0.f};

  // software B-prefetch one k-step ahead (global, L2-hot)
  bf16x8 bnx[4];
  #pragma unroll
  for (int c = 0; c < 4; ++c) bnx[c] = *(const bf16x8*)(wp + (size_t)c*16*DSEQ);

  #pragma unroll
  for (int half = 0; half < 2; ++half) {
    if (half) __syncthreads();       // everyone done reading half 0
    // ---- stage one 512-k half (64 rows x 512 k) ----
    if (BF16SRC) {
      // wave w stages rows w*16..w*16+15; one global_load_lds per row:
      // 64 lanes x 16 B -> linear 1 KB LDS row; source granule swizzled.
      const u16* Sv = Sb + ((size_t)b*L_ + (size_t)t*LT)*DSEQ + half*512;
      #pragma unroll
      for (int it = 0; it < 16; ++it) {
        const int row = wave*16 + it;
        const u16* gp = Sv + (size_t)row*DSEQ + ((lane ^ (row & 15)) << 3);
        u16* lp = Slds + row*512;    // wave-uniform LDS base
        __builtin_amdgcn_global_load_lds(
            (const __attribute__((address_space(1))) void*)gp,
            (__attribute__((address_space(3))) void*)lp, 16, 0, 0);
      }
    } else {
      // fp32 fallback: register staging with write-side swizzle
      const float* Sv = S + ((size_t)b*L_ + (size_t)t*LT)*DSEQ + half*512;
      #pragma unroll 2
      for (int it = 0; it < 16; ++it) {
        int f = it*256 + tid, row = f >> 6, g = f & 63;
        const float4* sp = (const float4*)(Sv + (size_t)row*DSEQ + g*8);
        float4 v0 = sp[0], v1 = sp[1];
        bf16x8 wv;
        wv[0]=(short)f2bf(v0.x); wv[1]=(short)f2bf(v0.y);
        wv[2]=(short)f2bf(v0.z); wv[3]=(short)f2bf(v0.w);
        wv[4]=(short)f2bf(v1.x); wv[5]=(short)f2bf(v1.y);
        wv[6]=(short)f2bf(v1.z); wv[7]=(short)f2bf(v1.w);
        *(bf16x8*)((char*)Slds + row*1024 + ((g*16) ^ ((row & 15) << 4))) = wv;
      }
    }
    __syncthreads();   // drains vmcnt -> all LDS rows complete

    #pragma unroll 2
    for (int k0 = 0; k0 < 512; k0 += 32) {
      bf16x8 bc[4];
      #pragma unroll
      for (int c = 0; c < 4; ++c) bc[c] = bnx[c];
      const int kn = (half*512 + k0 + 32) & (DSEQ - 1);  // global next k
      #pragma unroll
      for (int c = 0; c < 4; ++c)
        bnx[c] = *(const bf16x8*)(wp + (size_t)c*16*DSEQ + kn);

      const int colb = (k0*2 + lhi*16) ^ swz;
      #pragma unroll
      for (int rt = 0; rt < 4; ++rt) {
        bf16x8 af = *(const bf16x8*)((const char*)Slds + (arow[rt] + colb));
        acc[rt][0] = __builtin_amdgcn_mfma_f32_16x16x32_bf16(af, bc[0], acc[rt][0], 0,0,0);
        acc[rt][1] = __builtin_amdgcn_mfma_f32_16x16x32_bf16(af, bc[1], acc[rt][1], 0,0,0);
        acc[rt][2] = __builtin_amdgcn_mfma_f32_16x16x32_bf16(af, bc[2], acc[rt][2], 0,0,0);
        acc[rt][3] = __builtin_amdgcn_mfma_f32_16x16x32_bf16(af, bc[3], acc[rt][3], 0,0,0);
      }
    }
  }

  if (!isV) {
    // K-proj: tanh, dot with Q over 64 k-cols, reduce -> logit per row
    const float* Qb = Q + ((size_t)b*H_ + h)*DK_;
    float q[4];
    #pragma unroll
    for (int c = 0; c < 4; ++c) q[c] = Qb[16*c + llo];
    #pragma unroll
    for (int rt = 0; rt < 4; ++rt) {
      #pragma unroll
      for (int r = 0; r < 4; ++r) {
        float pl = q[0]*tanhf(acc[rt][0][r]) + q[1]*tanhf(acc[rt][1][r])
                 + q[2]*tanhf(acc[rt][2][r]) + q[3]*tanhf(acc[rt][3][r]);
        pl += __shfl_xor(pl, 1); pl += __shfl_xor(pl, 2);
        pl += __shfl_xor(pl, 4); pl += __shfl_xor(pl, 8);
        if (llo == 0) lpart[hp][rt*16 + lhi*4 + r] = pl;
      }
    }
  } else {
    // V-proj: exact gelu in place
    #pragma unroll
    for (int rt = 0; rt < 4; ++rt)
      #pragma unroll
      for (int c = 0; c < 4; ++c)
        #pragma unroll
        for (int r = 0; r < 4; ++r) {
          float x = acc[rt][c][r];
          acc[rt][c][r] = 0.5f*x*(1.f + erff(x*0.70710678118654752f));
        }
  }
  __syncthreads();

  if (isV) {
    // softmax stats over this tile's 64 rows (lane <-> row)
    float lg = lpart[hp][lane] * 0.125f;   // 1/sqrt(64)
    float mx = lg;
    #pragma unroll
    for (int mk = 1; mk < 64; mk <<= 1) mx = fmaxf(mx, __shfl_xor(mx, mk));
    float ev = __expf(lg - mx);
    float sv = ev;
    #pragma unroll
    for (int mk = 1; mk < 64; mk <<= 1) sv += __shfl_xor(sv, mk);

    float er[16];
    #pragma unroll
    for (int rt = 0; rt < 4; ++rt)
      #pragma unroll
      for (int r = 0; r < 4; ++r)
        er[rt*4 + r] = __shfl(ev, rt*16 + lhi*4 + r);

    float* pt = part + (((size_t)b*H_ + h)*NT + t)*PSTRIDE;
    #pragma unroll
    for (int c = 0; c < 4; ++c) {
      float y = 0.f;
      #pragma unroll
      for (int rt = 0; rt < 4; ++rt)
        #pragma unroll
        for (int r = 0; r < 4; ++r)
          y += er[rt*4 + r]*acc[rt][c][r];
      y += __shfl_xor(y, 16); y += __shfl_xor(y, 32);
      if (lhi == 0) pt[2 + 16*c + llo] = y;
    }
    if (lane == 0) { pt[0] = mx; pt[1] = sv; }
  }
}

// merge NT tile-partials per (b,h); grid (H, B), block 64 (v = thread)
__global__ void finalize_kernel(const float* __restrict__ part,
                                float* __restrict__ out) {
  const int h = blockIdx.x, b = blockIdx.y, v = threadIdx.x;
  const float* p = part + ((size_t)b*H_ + h)*(size_t)NT*PSTRIDE;
  float M = -3.0e38f;
  for (int tt = 0; tt < NT; ++tt) M = fmaxf(M, p[tt*PSTRIDE]);
  float ss = 0.f, y = 0.f;
  for (int tt = 0; tt < NT; ++tt) {
    float w = expf(p[tt*PSTRIDE] - M);
    ss += w*p[tt*PSTRIDE + 1];
    y  += w*p[tt*PSTRIDE + 2 + v];
  }
  out[((size_t)b*H_ + h)*DV_ + v] = y/ss;
}

extern "C" void kernel_launch(void* const* d_in, const int* in_sizes, int n_in,
                              void* d_out, int out_size, void* d_ws, size_t ws_size,
                              hipStream_t stream) {
  const float* X  = (const float*)d_in[0];
  const float* S  = (const float*)d_in[1];
  const float* Wq = (const float*)d_in[2];
  const float* Wk = (const float*)d_in[3];
  const float* Wv = (const float*)d_in[4];
  float* out = (float*)d_out;

  char* ws = (char*)d_ws;
  u16*   Wc   = (u16*)ws;                              // 4 MiB
  float* Qbuf = (float*)(ws + (4u<<20));               // 128 KiB
  float* part = (float*)(ws + (4u<<20) + (128u<<10));  // ~4.3 MiB
  u16*   Sb   = (u16*)(ws + (16u<<20));                // 128 MiB (optional)
  const bool useBf = ws_size >= (144ull << 20);

  pack_w_kernel  <<<dim3(H_, 128),  256, 0, stream>>>(Wk, Wv, Wc);
  q_proj_kernel  <<<dim3(H_, B_/4),  64, 0, stream>>>(X, Wq, Qbuf);
  if (useBf) {
    s2bf_kernel       <<<dim3(4096), 256, 0, stream>>>(S, Sb);
    fused_kernel<1>   <<<dim3(NT*B_*8), 256, 0, stream>>>(S, Sb, Wc, Qbuf, part);
  } else {
    fused_kernel<0>   <<<dim3(NT*B_*8), 256, 0, stream>>>(S, Sb, Wc, Qbuf, part);
  }
  finalize_kernel<<<dim3(H_, B_),    64, 0, stream>>>(part, out);
}

// Round 7
// 606.155 us; speedup vs baseline: 1.2544x; 1.2544x over previous
//
#include <hip/hip_runtime.h>
#include <math.h>

#define B_   32
#define L_   2048
#define DSEQ 1024
#define DGLB 1024
#define H_   16
#define DK_  64
#define DV_  64
#define LT   64
#define NT   (L_/LT)      // 32
#define PSTRIDE 66        // m, s, y[64]

// Wc2 layout: [h][ks(32)][j(128)][e(32)] bf16; d = ks*32 + e
#define WC_KSTRIDE 4096            // 128*32 elems per k-step
#define WC_HSTRIDE 131072          // 32*4096 elems per head

using u16    = unsigned short;
using bf16x8 = __attribute__((ext_vector_type(8))) short;
using f32x4  = __attribute__((ext_vector_type(4))) float;

__device__ __forceinline__ u16 f2bf(float x) {
  union { float f; unsigned int u; } v; v.f = x;
  return (u16)((v.u + 0x7fffu + ((v.u >> 16) & 1u)) >> 16);   // RNE
}

// Wc2[h][d>>5][j][d&31]: j<64 -> Wk[h,:,j], else Wv[h,:,j-64]
// One contiguous 1 KB block per (h,ks,16-row group) => B-frag loads coalesce
// across all 16 L2 channels (fixes the 2 KB-stride channel aliasing).
__global__ void pack_w_kernel(const float* __restrict__ Wk,
                              const float* __restrict__ Wv,
                              u16* __restrict__ Wc) {
  const int h = blockIdx.x, j = blockIdx.y;
  const float* src = (j < DK_) ? (Wk + (size_t)h*DSEQ*DK_ + j)
                               : (Wv + (size_t)h*DSEQ*DV_ + (j - DK_));
  u16* dst = Wc + (size_t)h*WC_HSTRIDE + (size_t)j*32;
  for (int d = threadIdx.x; d < DSEQ; d += blockDim.x)
    dst[(size_t)(d >> 5)*WC_KSTRIDE + (d & 31)] = f2bf(src[(size_t)d*64]);
}

// S (fp32) -> Sb (bf16), flat; 8-elem granules, coalesced
__global__ void s2bf_kernel(const float* __restrict__ S, u16* __restrict__ Sb) {
  const size_t G = (size_t)B_*L_*DSEQ/8;
  for (size_t i = (size_t)blockIdx.x*256 + threadIdx.x; i < G; i += (size_t)4096*256) {
    const float4* sp = (const float4*)(S + i*8);
    float4 v0 = sp[0], v1 = sp[1];
    bf16x8 wv;
    wv[0]=(short)f2bf(v0.x); wv[1]=(short)f2bf(v0.y);
    wv[2]=(short)f2bf(v0.z); wv[3]=(short)f2bf(v0.w);
    wv[4]=(short)f2bf(v1.x); wv[5]=(short)f2bf(v1.y);
    wv[6]=(short)f2bf(v1.z); wv[7]=(short)f2bf(v1.w);
    *(bf16x8*)(Sb + i*8) = wv;
  }
}

// Q[b][h][k] = tanh(sum_d X[b,d]*Wq[h,d,k]); grid (H, B/4), block 64
__global__ void q_proj_kernel(const float* __restrict__ X,
                              const float* __restrict__ Wq,
                              float* __restrict__ Q) {
  const int h = blockIdx.x, b0 = blockIdx.y*4, k = threadIdx.x;
  const float* w = Wq + (size_t)h*DGLB*DK_ + k;
  float a0=0.f, a1=0.f, a2=0.f, a3=0.f;
  for (int d = 0; d < DGLB; ++d) {
    float wv = w[(size_t)d*DK_];
    a0 += X[(size_t)(b0+0)*DGLB + d]*wv;
    a1 += X[(size_t)(b0+1)*DGLB + d]*wv;
    a2 += X[(size_t)(b0+2)*DGLB + d]*wv;
    a3 += X[(size_t)(b0+3)*DGLB + d]*wv;
  }
  Q[((size_t)(b0+0)*H_+h)*DK_+k] = tanhf(a0);
  Q[((size_t)(b0+1)*H_+h)*DK_+k] = tanhf(a1);
  Q[((size_t)(b0+2)*H_+h)*DK_+k] = tanhf(a2);
  Q[((size_t)(b0+3)*H_+h)*DK_+k] = tanhf(a3);
}

// grid: 8192 linear blocks, 256 threads = 4 waves.
// slot=id&7 -> XCD; each slot owns 2 heads (Wc2 slice 512 KB, L2-hot).
// Wave w = (head hp=w>>1, K|V=w&1); tile 64 rows x 64 cols, acc[4][4].
// __launch_bounds__(256,2): 256-reg budget (spill-free, r6-verified) and
// 2 blocks/CU so staging overlaps the other block's k-loop.
// B-frag loads: contiguous 1 KB from Wc2 (channel-balanced), prefetch 1 step.
// A staged bf16 via global_load_lds, swizzle on global source granule (T21).
template<int BF16SRC>
__global__ __launch_bounds__(256, 2) void fused_kernel(
    const float* __restrict__ S, const u16* __restrict__ Sb,
    const u16* __restrict__ Wc, const float* __restrict__ Q,
    float* __restrict__ part) {
  __shared__ u16   Slds[LT*512];     // 64 KB, rows 1 KB
  __shared__ float lpart[2][64];

  const int id   = blockIdx.x;
  const int slot = id & 7;           // XCD / head-pair group
  const int rest = id >> 3;
  const int t    = rest & (NT-1), b = rest >> 5;

  const int tid  = threadIdx.x;
  const int wave = tid >> 6, lane = tid & 63;
  const int lhi  = lane >> 4, llo = lane & 15;
  const int isV  = wave & 1,  hp  = wave >> 1;
  const int h    = slot*2 + hp;

  // per-lane B base: head h, rows isV*64 + llo (+c*16), elems lhi*8
  const u16* wb = Wc + (size_t)h*WC_HSTRIDE + (size_t)(isV*64 + llo)*32 + lhi*8;
  const int swz = llo << 4;
  int arow[4];
  #pragma unroll
  for (int rt = 0; rt < 4; ++rt) arow[rt] = (rt*16 + llo)*1024;  // bytes

  f32x4 acc[4][4];
  #pragma unroll
  for (int rt = 0; rt < 4; ++rt)
    #pragma unroll
    for (int c = 0; c < 4; ++c) acc[rt][c] = {0.f,0.f,0.f,0.f};

  // software B-prefetch one k-step ahead (contiguous, L2-hot)
  bf16x8 bnx[4];
  #pragma unroll
  for (int c = 0; c < 4; ++c) bnx[c] = *(const bf16x8*)(wb + c*512);

  #pragma unroll
  for (int half = 0; half < 2; ++half) {
    if (half) __syncthreads();       // everyone done reading half 0
    // ---- stage one 512-k half (64 rows x 512 k) ----
    if (BF16SRC) {
      // wave w stages rows w*16..w*16+15; one global_load_lds per row:
      // 64 lanes x 16 B -> linear 1 KB LDS row; source granule swizzled.
      const u16* Sv = Sb + ((size_t)b*L_ + (size_t)t*LT)*DSEQ + half*512;
      #pragma unroll
      for (int it = 0; it < 16; ++it) {
        const int row = wave*16 + it;
        const u16* gp = Sv + (size_t)row*DSEQ + ((lane ^ (row & 15)) << 3);
        u16* lp = Slds + row*512;    // wave-uniform LDS base
        __builtin_amdgcn_global_load_lds(
            (const __attribute__((address_space(1))) void*)gp,
            (__attribute__((address_space(3))) void*)lp, 16, 0, 0);
      }
    } else {
      // fp32 fallback: register staging with write-side swizzle
      const float* Sv = S + ((size_t)b*L_ + (size_t)t*LT)*DSEQ + half*512;
      #pragma unroll 2
      for (int it = 0; it < 16; ++it) {
        int f = it*256 + tid, row = f >> 6, g = f & 63;
        const float4* sp = (const float4*)(Sv + (size_t)row*DSEQ + g*8);
        float4 v0 = sp[0], v1 = sp[1];
        bf16x8 wv;
        wv[0]=(short)f2bf(v0.x); wv[1]=(short)f2bf(v0.y);
        wv[2]=(short)f2bf(v0.z); wv[3]=(short)f2bf(v0.w);
        wv[4]=(short)f2bf(v1.x); wv[5]=(short)f2bf(v1.y);
        wv[6]=(short)f2bf(v1.z); wv[7]=(short)f2bf(v1.w);
        *(bf16x8*)((char*)Slds + row*1024 + ((g*16) ^ ((row & 15) << 4))) = wv;
      }
    }
    __syncthreads();   // drains vmcnt -> all LDS rows complete

    #pragma unroll 2
    for (int kk = 0; kk < 16; ++kk) {
      bf16x8 bc[4];
      #pragma unroll
      for (int c = 0; c < 4; ++c) bc[c] = bnx[c];
      const int ksn = (half*16 + kk + 1) & 31;   // next global k-step
      #pragma unroll
      for (int c = 0; c < 4; ++c)
        bnx[c] = *(const bf16x8*)(wb + (size_t)ksn*WC_KSTRIDE + c*512);

      const int colb = (kk*64 + lhi*16) ^ swz;
      #pragma unroll
      for (int rt = 0; rt < 4; ++rt) {
        bf16x8 af = *(const bf16x8*)((const char*)Slds + (arow[rt] + colb));
        acc[rt][0] = __builtin_amdgcn_mfma_f32_16x16x32_bf16(af, bc[0], acc[rt][0], 0,0,0);
        acc[rt][1] = __builtin_amdgcn_mfma_f32_16x16x32_bf16(af, bc[1], acc[rt][1], 0,0,0);
        acc[rt][2] = __builtin_amdgcn_mfma_f32_16x16x32_bf16(af, bc[2], acc[rt][2], 0,0,0);
        acc[rt][3] = __builtin_amdgcn_mfma_f32_16x16x32_bf16(af, bc[3], acc[rt][3], 0,0,0);
      }
    }
  }

  if (!isV) {
    // K-proj: tanh, dot with Q over 64 k-cols, reduce -> logit per row
    const float* Qb = Q + ((size_t)b*H_ + h)*DK_;
    float q[4];
    #pragma unroll
    for (int c = 0; c < 4; ++c) q[c] = Qb[16*c + llo];
    #pragma unroll
    for (int rt = 0; rt < 4; ++rt) {
      #pragma unroll
      for (int r = 0; r < 4; ++r) {
        float pl = q[0]*tanhf(acc[rt][0][r]) + q[1]*tanhf(acc[rt][1][r])
                 + q[2]*tanhf(acc[rt][2][r]) + q[3]*tanhf(acc[rt][3][r]);
        pl += __shfl_xor(pl, 1); pl += __shfl_xor(pl, 2);
        pl += __shfl_xor(pl, 4); pl += __shfl_xor(pl, 8);
        if (llo == 0) lpart[hp][rt*16 + lhi*4 + r] = pl;
      }
    }
  } else {
    // V-proj: exact gelu in place
    #pragma unroll
    for (int rt = 0; rt < 4; ++rt)
      #pragma unroll
      for (int c = 0; c < 4; ++c)
        #pragma unroll
        for (int r = 0; r < 4; ++r) {
          float x = acc[rt][c][r];
          acc[rt][c][r] = 0.5f*x*(1.f + erff(x*0.70710678118654752f));
        }
  }
  __syncthreads();

  if (isV) {
    // softmax stats over this tile's 64 rows (lane <-> row)
    float lg = lpart[hp][lane] * 0.125f;   // 1/sqrt(64)
    float mx = lg;
    #pragma unroll
    for (int mk = 1; mk < 64; mk <<= 1) mx = fmaxf(mx, __shfl_xor(mx, mk));
    float ev = __expf(lg - mx);
    float sv = ev;
    #pragma unroll
    for (int mk = 1; mk < 64; mk <<= 1) sv += __shfl_xor(sv, mk);

    float er[16];
    #pragma unroll
    for (int rt = 0; rt < 4; ++rt)
      #pragma unroll
      for (int r = 0; r < 4; ++r)
        er[rt*4 + r] = __shfl(ev, rt*16 + lhi*4 + r);

    float* pt = part + (((size_t)b*H_ + h)*NT + t)*PSTRIDE;
    #pragma unroll
    for (int c = 0; c < 4; ++c) {
      float y = 0.f;
      #pragma unroll
      for (int rt = 0; rt < 4; ++rt)
        #pragma unroll
        for (int r = 0; r < 4; ++r)
          y += er[rt*4 + r]*acc[rt][c][r];
      y += __shfl_xor(y, 16); y += __shfl_xor(y, 32);
      if (lhi == 0) pt[2 + 16*c + llo] = y;
    }
    if (lane == 0) { pt[0] = mx; pt[1] = sv; }
  }
}

// merge NT tile-partials per (b,h); grid (H, B), block 64 (v = thread)
__global__ void finalize_kernel(const float* __restrict__ part,
                                float* __restrict__ out) {
  const int h = blockIdx.x, b = blockIdx.y, v = threadIdx.x;
  const float* p = part + ((size_t)b*H_ + h)*(size_t)NT*PSTRIDE;
  float M = -3.0e38f;
  for (int tt = 0; tt < NT; ++tt) M = fmaxf(M, p[tt*PSTRIDE]);
  float ss = 0.f, y = 0.f;
  for (int tt = 0; tt < NT; ++tt) {
    float w = expf(p[tt*PSTRIDE] - M);
    ss += w*p[tt*PSTRIDE + 1];
    y  += w*p[tt*PSTRIDE + 2 + v];
  }
  out[((size_t)b*H_ + h)*DV_ + v] = y/ss;
}

extern "C" void kernel_launch(void* const* d_in, const int* in_sizes, int n_in,
                              void* d_out, int out_size, void* d_ws, size_t ws_size,
                              hipStream_t stream) {
  const float* X  = (const float*)d_in[0];
  const float* S  = (const float*)d_in[1];
  const float* Wq = (const float*)d_in[2];
  const float* Wk = (const float*)d_in[3];
  const float* Wv = (const float*)d_in[4];
  float* out = (float*)d_out;

  char* ws = (char*)d_ws;
  u16*   Wc   = (u16*)ws;                              // 4 MiB
  float* Qbuf = (float*)(ws + (4u<<20));               // 128 KiB
  float* part = (float*)(ws + (4u<<20) + (128u<<10));  // ~4.3 MiB
  u16*   Sb   = (u16*)(ws + (16u<<20));                // 128 MiB (optional)
  const bool useBf = ws_size >= (144ull << 20);

  pack_w_kernel  <<<dim3(H_, 128),  256, 0, stream>>>(Wk, Wv, Wc);
  q_proj_kernel  <<<dim3(H_, B_/4),  64, 0, stream>>>(X, Wq, Qbuf);
  if (useBf) {
    s2bf_kernel       <<<dim3(4096), 256, 0, stream>>>(S, Sb);
    fused_kernel<1>   <<<dim3(NT*B_*8), 256, 0, stream>>>(S, Sb, Wc, Qbuf, part);
  } else {
    fused_kernel<0>   <<<dim3(NT*B_*8), 256, 0, stream>>>(S, Sb, Wc, Qbuf, part);
  }
  finalize_kernel<<<dim3(H_, B_),    64, 0, stream>>>(part, out);
}

// Round 8
// 522.866 us; speedup vs baseline: 1.4542x; 1.1593x over previous
//
#include <hip/hip_runtime.h>
#include <math.h>

#define B_   32
#define L_   2048
#define DSEQ 1024
#define DGLB 1024
#define H_   16
#define DK_  64
#define DV_  64
#define LT   64
#define NT   (L_/LT)      // 32
#define PSTRIDE 66        // m, s, y[64]

// Wc2 layout: [h][ks(32)][j(128)][e(32)] bf16; d = ks*32 + e
#define WC_KSTRIDE 4096            // 128*32 elems per k-step
#define WC_HSTRIDE 131072          // 32*4096 elems per head

#define AS1 __attribute__((address_space(1)))
#define AS3 __attribute__((address_space(3)))

using u16    = unsigned short;
using bf16x8 = __attribute__((ext_vector_type(8))) short;
using f32x4  = __attribute__((ext_vector_type(4))) float;

__device__ __forceinline__ u16 f2bf(float x) {
  union { float f; unsigned int u; } v; v.f = x;
  return (u16)((v.u + 0x7fffu + ((v.u >> 16) & 1u)) >> 16);   // RNE
}

// Wc2[h][d>>5][j][d&31]: j<64 -> Wk[h,:,j], else Wv[h,:,j-64]
__global__ void pack_w_kernel(const float* __restrict__ Wk,
                              const float* __restrict__ Wv,
                              u16* __restrict__ Wc) {
  const int h = blockIdx.x, j = blockIdx.y;
  const float* src = (j < DK_) ? (Wk + (size_t)h*DSEQ*DK_ + j)
                               : (Wv + (size_t)h*DSEQ*DV_ + (j - DK_));
  u16* dst = Wc + (size_t)h*WC_HSTRIDE + (size_t)j*32;
  for (int d = threadIdx.x; d < DSEQ; d += blockDim.x)
    dst[(size_t)(d >> 5)*WC_KSTRIDE + (d & 31)] = f2bf(src[(size_t)d*64]);
}

// S (fp32) -> Sb (bf16), flat; 8-elem granules, coalesced
__global__ void s2bf_kernel(const float* __restrict__ S, u16* __restrict__ Sb) {
  const size_t G = (size_t)B_*L_*DSEQ/8;
  for (size_t i = (size_t)blockIdx.x*256 + threadIdx.x; i < G; i += (size_t)4096*256) {
    const float4* sp = (const float4*)(S + i*8);
    float4 v0 = sp[0], v1 = sp[1];
    bf16x8 wv;
    wv[0]=(short)f2bf(v0.x); wv[1]=(short)f2bf(v0.y);
    wv[2]=(short)f2bf(v0.z); wv[3]=(short)f2bf(v0.w);
    wv[4]=(short)f2bf(v1.x); wv[5]=(short)f2bf(v1.y);
    wv[6]=(short)f2bf(v1.z); wv[7]=(short)f2bf(v1.w);
    *(bf16x8*)(Sb + i*8) = wv;
  }
}

// Q[b][h][k] = tanh(sum_d X[b,d]*Wq[h,d,k]); grid (H, B/4), block 64
__global__ void q_proj_kernel(const float* __restrict__ X,
                              const float* __restrict__ Wq,
                              float* __restrict__ Q) {
  const int h = blockIdx.x, b0 = blockIdx.y*4, k = threadIdx.x;
  const float* w = Wq + (size_t)h*DGLB*DK_ + k;
  float a0=0.f, a1=0.f, a2=0.f, a3=0.f;
  for (int d = 0; d < DGLB; ++d) {
    float wv = w[(size_t)d*DK_];
    a0 += X[(size_t)(b0+0)*DGLB + d]*wv;
    a1 += X[(size_t)(b0+1)*DGLB + d]*wv;
    a2 += X[(size_t)(b0+2)*DGLB + d]*wv;
    a3 += X[(size_t)(b0+3)*DGLB + d]*wv;
  }
  Q[((size_t)(b0+0)*H_+h)*DK_+k] = tanhf(a0);
  Q[((size_t)(b0+1)*H_+h)*DK_+k] = tanhf(a1);
  Q[((size_t)(b0+2)*H_+h)*DK_+k] = tanhf(a2);
  Q[((size_t)(b0+3)*H_+h)*DK_+k] = tanhf(a3);
}

// grid: 8192 linear blocks, 256 threads = 4 waves, 2 blocks/CU.
// slot=id&7 -> XCD; slot owns 2 heads (Wc2 slice 512 KB, L2-hot).
// Wave w = (head hp=w>>1, K|V=w&1); tile 64 rows x 64 cols, acc[4][4].
// K pipelined in 4 sub-tiles of 256 via 2x32KB LDS double-buffer:
// iter s issues STAGE(s+1) FIRST, computes buf[s&1], then one barrier
// (vmcnt drain lands after ~1600cy of compute >= HBM latency).
// B prefetched distance 2 (bA/bB, static names). setprio(1) around MFMA.
template<int BF16SRC>
__global__ __launch_bounds__(256, 2) void fused_kernel(
    const float* __restrict__ S, const u16* __restrict__ Sb,
    const u16* __restrict__ Wc, const float* __restrict__ Q,
    float* __restrict__ part) {
  __shared__ u16   Slds[2*64*256];   // 2 x 32 KB, rows 512 B
  __shared__ float lpart[2][64];

  const int id   = blockIdx.x;
  const int slot = id & 7;           // XCD / head-pair group
  const int rest = id >> 3;
  const int t    = rest & (NT-1), b = rest >> 5;

  const int tid  = threadIdx.x;
  const int wave = tid >> 6, lane = tid & 63;
  const int lhi  = lane >> 4, llo = lane & 15;
  const int isV  = wave & 1,  hp  = wave >> 1;
  const int h    = slot*2 + hp;

  const u16* wb = Wc + (size_t)h*WC_HSTRIDE + (size_t)(isV*64 + llo)*32 + lhi*8;
  const int swz = llo << 4;
  int arow[4];
  #pragma unroll
  for (int rt = 0; rt < 4; ++rt) arow[rt] = (rt*16 + llo)*512;  // bytes

  const u16*   Sv = Sb + ((size_t)b*L_ + (size_t)t*LT)*DSEQ;
  const float* Sf = S  + ((size_t)b*L_ + (size_t)t*LT)*DSEQ;

  // stage sub-tile (64 rows x 256 k) into buf[sub&1] via global_load_lds:
  // chunk j (1 KB LDS) = rows 2j,2j+1; lane l -> row 2j+(l>>5), pos q=l&31,
  // logical granule g = q ^ (row&15) fetched from global (src-side swizzle).
  auto stage_gl = [&](int sub) {
    const int bs = (sub & 1) * 16384;          // u16 offset
    #pragma unroll
    for (int it = 0; it < 8; ++it) {
      const int j   = wave*8 + it;
      const int row = 2*j + (lane >> 5);
      const int g   = (lane & 31) ^ (row & 15);
      const u16* gp = Sv + (size_t)row*DSEQ + sub*256 + (g << 3);
      __builtin_amdgcn_global_load_lds(
          (const AS1 void*)gp, (AS3 void*)(Slds + bs + j*512), 16, 0, 0);
    }
  };
  auto stage_reg = [&](int sub) {              // fp32 fallback
    const int bs = (sub & 1) * 32768;          // bytes
    #pragma unroll 2
    for (int it = 0; it < 8; ++it) {
      int f = it*256 + tid, row = f >> 5, q = f & 31;
      int g = q ^ (row & 15);
      const float4* sp = (const float4*)(Sf + (size_t)row*DSEQ + sub*256 + g*8);
      float4 v0 = sp[0], v1 = sp[1];
      bf16x8 wv;
      wv[0]=(short)f2bf(v0.x); wv[1]=(short)f2bf(v0.y);
      wv[2]=(short)f2bf(v0.z); wv[3]=(short)f2bf(v0.w);
      wv[4]=(short)f2bf(v1.x); wv[5]=(short)f2bf(v1.y);
      wv[6]=(short)f2bf(v1.z); wv[7]=(short)f2bf(v1.w);
      *(bf16x8*)((char*)Slds + bs + row*512 + q*16) = wv;
    }
  };

  f32x4 acc[4][4];
  #pragma unroll
  for (int rt = 0; rt < 4; ++rt)
    #pragma unroll
    for (int c = 0; c < 4; ++c) acc[rt][c] = {0.f,0.f,0.f,0.f};

  bf16x8 bA[4], bB[4];                         // B prefetch, distance 2
  if (BF16SRC) stage_gl(0);
  #pragma unroll
  for (int c = 0; c < 4; ++c) bA[c] = *(const bf16x8*)(wb + c*512);
  #pragma unroll
  for (int c = 0; c < 4; ++c) bB[c] = *(const bf16x8*)(wb + WC_KSTRIDE + c*512);
  if (BF16SRC) __syncthreads();

  #pragma unroll
  for (int s = 0; s < 4; ++s) {
    if (BF16SRC) {
      if (s < 3) stage_gl(s + 1);              // issue-early
    } else {
      stage_reg(s);
      __syncthreads();
    }
    const char* cb = (const char*)Slds + (s & 1)*32768;
    #pragma unroll
    for (int kk = 0; kk < 8; kk += 2) {
      const int ks = s*8 + kk;
      { // even step: consume bA, refill for ks+2
        const int colb = (kk*64 + lhi*16) ^ swz;
        __builtin_amdgcn_s_setprio(1);
        #pragma unroll
        for (int rt = 0; rt < 4; ++rt) {
          bf16x8 af = *(const bf16x8*)(cb + arow[rt] + colb);
          acc[rt][0] = __builtin_amdgcn_mfma_f32_16x16x32_bf16(af, bA[0], acc[rt][0], 0,0,0);
          acc[rt][1] = __builtin_amdgcn_mfma_f32_16x16x32_bf16(af, bA[1], acc[rt][1], 0,0,0);
          acc[rt][2] = __builtin_amdgcn_mfma_f32_16x16x32_bf16(af, bA[2], acc[rt][2], 0,0,0);
          acc[rt][3] = __builtin_amdgcn_mfma_f32_16x16x32_bf16(af, bA[3], acc[rt][3], 0,0,0);
        }
        __builtin_amdgcn_s_setprio(0);
        const int kn = (ks + 2) & 31;
        #pragma unroll
        for (int c = 0; c < 4; ++c)
          bA[c] = *(const bf16x8*)(wb + (size_t)kn*WC_KSTRIDE + c*512);
      }
      { // odd step: consume bB, refill for ks+3
        const int colb = ((kk+1)*64 + lhi*16) ^ swz;
        __builtin_amdgcn_s_setprio(1);
        #pragma unroll
        for (int rt = 0; rt < 4; ++rt) {
          bf16x8 af = *(const bf16x8*)(cb + arow[rt] + colb);
          acc[rt][0] = __builtin_amdgcn_mfma_f32_16x16x32_bf16(af, bB[0], acc[rt][0], 0,0,0);
          acc[rt][1] = __builtin_amdgcn_mfma_f32_16x16x32_bf16(af, bB[1], acc[rt][1], 0,0,0);
          acc[rt][2] = __builtin_amdgcn_mfma_f32_16x16x32_bf16(af, bB[2], acc[rt][2], 0,0,0);
          acc[rt][3] = __builtin_amdgcn_mfma_f32_16x16x32_bf16(af, bB[3], acc[rt][3], 0,0,0);
        }
        __builtin_amdgcn_s_setprio(0);
        const int kn = (ks + 3) & 31;
        #pragma unroll
        for (int c = 0; c < 4; ++c)
          bB[c] = *(const bf16x8*)(wb + (size_t)kn*WC_KSTRIDE + c*512);
      }
    }
    __syncthreads();
  }

  if (!isV) {
    // K-proj: tanh, dot with Q over 64 k-cols, reduce -> logit per row
    const float* Qb = Q + ((size_t)b*H_ + h)*DK_;
    float q[4];
    #pragma unroll
    for (int c = 0; c < 4; ++c) q[c] = Qb[16*c + llo];
    #pragma unroll
    for (int rt = 0; rt < 4; ++rt) {
      #pragma unroll
      for (int r = 0; r < 4; ++r) {
        float pl = q[0]*tanhf(acc[rt][0][r]) + q[1]*tanhf(acc[rt][1][r])
                 + q[2]*tanhf(acc[rt][2][r]) + q[3]*tanhf(acc[rt][3][r]);
        pl += __shfl_xor(pl, 1); pl += __shfl_xor(pl, 2);
        pl += __shfl_xor(pl, 4); pl += __shfl_xor(pl, 8);
        if (llo == 0) lpart[hp][rt*16 + lhi*4 + r] = pl;
      }
    }
  } else {
    // V-proj: exact gelu in place
    #pragma unroll
    for (int rt = 0; rt < 4; ++rt)
      #pragma unroll
      for (int c = 0; c < 4; ++c)
        #pragma unroll
        for (int r = 0; r < 4; ++r) {
          float x = acc[rt][c][r];
          acc[rt][c][r] = 0.5f*x*(1.f + erff(x*0.70710678118654752f));
        }
  }
  __syncthreads();

  if (isV) {
    // softmax stats over this tile's 64 rows (lane <-> row)
    float lg = lpart[hp][lane] * 0.125f;   // 1/sqrt(64)
    float mx = lg;
    #pragma unroll
    for (int mk = 1; mk < 64; mk <<= 1) mx = fmaxf(mx, __shfl_xor(mx, mk));
    float ev = __expf(lg - mx);
    float sv = ev;
    #pragma unroll
    for (int mk = 1; mk < 64; mk <<= 1) sv += __shfl_xor(sv, mk);

    float er[16];
    #pragma unroll
    for (int rt = 0; rt < 4; ++rt)
      #pragma unroll
      for (int r = 0; r < 4; ++r)
        er[rt*4 + r] = __shfl(ev, rt*16 + lhi*4 + r);

    float* pt = part + (((size_t)b*H_ + h)*NT + t)*PSTRIDE;
    #pragma unroll
    for (int c = 0; c < 4; ++c) {
      float y = 0.f;
      #pragma unroll
      for (int rt = 0; rt < 4; ++rt)
        #pragma unroll
        for (int r = 0; r < 4; ++r)
          y += er[rt*4 + r]*acc[rt][c][r];
      y += __shfl_xor(y, 16); y += __shfl_xor(y, 32);
      if (lhi == 0) pt[2 + 16*c + llo] = y;
    }
    if (lane == 0) { pt[0] = mx; pt[1] = sv; }
  }
}

// merge NT tile-partials per (b,h); grid (H, B), block 64 (v = thread)
__global__ void finalize_kernel(const float* __restrict__ part,
                                float* __restrict__ out) {
  const int h = blockIdx.x, b = blockIdx.y, v = threadIdx.x;
  const float* p = part + ((size_t)b*H_ + h)*(size_t)NT*PSTRIDE;
  float M = -3.0e38f;
  for (int tt = 0; tt < NT; ++tt) M = fmaxf(M, p[tt*PSTRIDE]);
  float ss = 0.f, y = 0.f;
  for (int tt = 0; tt < NT; ++tt) {
    float w = expf(p[tt*PSTRIDE] - M);
    ss += w*p[tt*PSTRIDE + 1];
    y  += w*p[tt*PSTRIDE + 2 + v];
  }
  out[((size_t)b*H_ + h)*DV_ + v] = y/ss;
}

extern "C" void kernel_launch(void* const* d_in, const int* in_sizes, int n_in,
                              void* d_out, int out_size, void* d_ws, size_t ws_size,
                              hipStream_t stream) {
  const float* X  = (const float*)d_in[0];
  const float* S  = (const float*)d_in[1];
  const float* Wq = (const float*)d_in[2];
  const float* Wk = (const float*)d_in[3];
  const float* Wv = (const float*)d_in[4];
  float* out = (float*)d_out;

  char* ws = (char*)d_ws;
  u16*   Wc   = (u16*)ws;                              // 4 MiB
  float* Qbuf = (float*)(ws + (4u<<20));               // 128 KiB
  float* part = (float*)(ws + (4u<<20) + (128u<<10));  // ~4.3 MiB
  u16*   Sb   = (u16*)(ws + (16u<<20));                // 128 MiB (optional)
  const bool useBf = ws_size >= (144ull << 20);

  pack_w_kernel  <<<dim3(H_, 128),  256, 0, stream>>>(Wk, Wv, Wc);
  q_proj_kernel  <<<dim3(H_, B_/4),  64, 0, stream>>>(X, Wq, Qbuf);
  if (useBf) {
    s2bf_kernel       <<<dim3(4096), 256, 0, stream>>>(S, Sb);
    fused_kernel<1>   <<<dim3(NT*B_*8), 256, 0, stream>>>(S, Sb, Wc, Qbuf, part);
  } else {
    fused_kernel<0>   <<<dim3(NT*B_*8), 256, 0, stream>>>(S, Sb, Wc, Qbuf, part);
  }
  finalize_kernel<<<dim3(H_, B_),    64, 0, stream>>>(part, out);
}